// Round 5
// baseline (422.166 us; speedup 1.0000x reference)
//
#include <hip/hip_runtime.h>

// SAGE_Net: 2-layer GraphSAGE, N=100k, E=1.6M, 128->128->64, fp32.
// R5: barrier-free LDS-free MFMA GEMMs. All operands pre-tiled into
// "k-chunk planes": plane c holds k=8c..8c+7 as 16 B per row, rows
// contiguous -> every MFMA fragment load is a coalesced dwordx4.
// Split precision: hi+lo bf16, terms Ah.Bh + Al.Bh + Ah.Bl (x-lo dropped).

typedef unsigned int uint32;
typedef short bf16x4 __attribute__((ext_vector_type(4)));
typedef short bf16x8 __attribute__((ext_vector_type(8)));
typedef float f32x16 __attribute__((ext_vector_type(16)));

__device__ __forceinline__ uint32 pack_bf16_rne(float a, float b) {
    uint32 ua = __float_as_uint(a);
    uint32 ub = __float_as_uint(b);
    uint32 ra = (ua + 0x7fffu + ((ua >> 16) & 1u)) >> 16;
    uint32 rb = (ub + 0x7fffu + ((ub >> 16) & 1u)) >> 16;
    return ra | (rb << 16);
}
__device__ __forceinline__ float bf_lo(uint32 v) { return __uint_as_float(v << 16); }
__device__ __forceinline__ float bf_hi(uint32 v) { return __uint_as_float(v & 0xffff0000u); }

__device__ __forceinline__ short rne16(float v, float* back) {
    uint32 u = __float_as_uint(v);
    uint32 r = (u + 0x7fffu + ((u >> 16) & 1u)) >> 16;
    *back = __uint_as_float(r << 16);
    return (short)r;
}

// x -> xb (row-major packed bf16 hi, for gathers) + xpH (hi planes for MFMA)
__global__ void k_to_bf16(const float* __restrict__ x, uint32* __restrict__ xb,
                          short* __restrict__ xpH, long n4, int spl) {
    long i = (long)blockIdx.x * blockDim.x + threadIdx.x;
    if (i >= n4) return;
    int node = (int)(i >> 5);
    int k4 = ((int)i & 31) * 4;
    float4 v = ((const float4*)x)[i];
    float back;
    bf16x4 hi4;
    hi4[0] = rne16(v.x, &back);
    hi4[1] = rne16(v.y, &back);
    hi4[2] = rne16(v.z, &back);
    hi4[3] = rne16(v.w, &back);
    uint2 oxb;
    oxb.x = (uint32)(unsigned short)hi4[0] | ((uint32)(unsigned short)hi4[1] << 16);
    oxb.y = (uint32)(unsigned short)hi4[2] | ((uint32)(unsigned short)hi4[3] << 16);
    ((uint2*)xb)[i] = oxb;
    int c = k4 >> 3;
    *(bf16x4*)&xpH[(size_t)c * spl + (size_t)node * 8 + (k4 & 7)] = hi4;
}

// weights -> hi/lo planes. W1: 32 planes (K=256, k<128->W1l else W1r), stride 1024 shorts.
// W2: 16 planes (K=128, j<64->W2l else W2r), stride 1024 shorts.
__global__ void k_wprep(const float* __restrict__ W1l, const float* __restrict__ W1r,
                        const float* __restrict__ W2l, const float* __restrict__ W2r,
                        short* __restrict__ W1pH, short* __restrict__ W1pL,
                        short* __restrict__ W2pH, short* __restrict__ W2pL) {
    int i = blockIdx.x * blockDim.x + threadIdx.x;
    float back;
    if (i < 32768) {
        int j = i >> 8, k = i & 255;
        float v = (k < 128) ? W1l[j * 128 + k] : W1r[j * 128 + k - 128];
        float hb;
        short hs = rne16(v, &hb);
        short ls = rne16(v - hb, &back);
        int idx = (k >> 3) * 1024 + j * 8 + (k & 7);
        W1pH[idx] = hs;
        W1pL[idx] = ls;
    } else if (i < 32768 + 16384) {
        int i2 = i - 32768;
        int j = i2 >> 7, k = i2 & 127;
        float v = (j < 64) ? W2l[j * 128 + k] : W2r[(j - 64) * 128 + k];
        float hb;
        short hs = rne16(v, &hb);
        short ls = rne16(v - hb, &back);
        int idx = (k >> 3) * 1024 + j * 8 + (k & 7);
        W2pH[idx] = hs;
        W2pL[idx] = ls;
    }
}

// ---- bucketed CSR build (unchanged from R3/R4) ----

__global__ void k_bcount(const int* __restrict__ ei, int E, int NB,
                         int* __restrict__ bucket_cnt) {
    __shared__ int hist[1024];
    int t = threadIdx.x;
    for (int i = t; i < NB; i += 256) hist[i] = 0;
    __syncthreads();
    int stride = gridDim.x * 256;
    for (int e = blockIdx.x * 256 + t; e < E; e += stride)
        atomicAdd(&hist[ei[E + e] >> 8], 1);
    __syncthreads();
    for (int i = t; i < NB; i += 256) {
        int c = hist[i];
        if (c) atomicAdd(&bucket_cnt[i], c);
    }
}

__global__ void k_bscan(const int* __restrict__ bucket_cnt, int NB, int E,
                        int* __restrict__ bucket_off, int* __restrict__ bucket_cur) {
    __shared__ int s[1024];
    int t = threadIdx.x;
    int v = (t < NB) ? bucket_cnt[t] : 0;
    s[t] = v;
    __syncthreads();
    for (int o = 1; o < 1024; o <<= 1) {
        int u = (t >= o) ? s[t - o] : 0;
        __syncthreads();
        s[t] += u;
        __syncthreads();
    }
    int ex = s[t] - v;
    if (t < NB) { bucket_off[t] = ex; bucket_cur[t] = ex; }
    if (t == NB - 1) bucket_off[NB] = ex + v;
}

__global__ void k_bscatter(const int* __restrict__ ei, int E, int NB,
                           int* __restrict__ bucket_cur, uint32* __restrict__ eb) {
    __shared__ int hist[1024];
    __shared__ int base[1024];
    int t = threadIdx.x;
    for (int i = t; i < NB; i += 256) hist[i] = 0;
    __syncthreads();
    int stride = gridDim.x * 256;
    for (int e = blockIdx.x * 256 + t; e < E; e += stride)
        atomicAdd(&hist[ei[E + e] >> 8], 1);
    __syncthreads();
    for (int i = t; i < NB; i += 256) {
        int c = hist[i];
        base[i] = c ? atomicAdd(&bucket_cur[i], c) : 0;
        hist[i] = 0;
    }
    __syncthreads();
    for (int e = blockIdx.x * 256 + t; e < E; e += stride) {
        int d = ei[E + e];
        int b = d >> 8;
        int r = atomicAdd(&hist[b], 1);
        eb[base[b] + r] = ((uint32)(d & 255) << 24) | (uint32)ei[e];
    }
}

__global__ void k_bfinal(const uint32* __restrict__ eb,
                         const int* __restrict__ bucket_off,
                         int* __restrict__ row_ptr, int* __restrict__ col,
                         int N, int E) {
    __shared__ int deg[256];
    __shared__ int sc[256];
    __shared__ int cur[256];
    int b = blockIdx.x;
    int t = threadIdx.x;
    int beg = bucket_off[b], end = bucket_off[b + 1];
    deg[t] = 0;
    __syncthreads();
    for (int e = beg + t; e < end; e += 256)
        atomicAdd(&deg[eb[e] >> 24], 1);
    __syncthreads();
    int v = deg[t];
    sc[t] = v;
    __syncthreads();
    for (int o = 1; o < 256; o <<= 1) {
        int u = (t >= o) ? sc[t - o] : 0;
        __syncthreads();
        sc[t] += u;
        __syncthreads();
    }
    int ex = sc[t] - v;
    int node = b * 256 + t;
    if (node < N) row_ptr[node] = beg + ex;
    if (b == gridDim.x - 1 && t == 0) row_ptr[N] = E;
    cur[t] = ex;
    __syncthreads();
    for (int e = beg + t; e < end; e += 256) {
        uint32 u = eb[e];
        int r = atomicAdd(&cur[u >> 24], 1);
        col[beg + r] = (int)(u & 0xFFFFFFu);
    }
}

// ---- aggregation 1: gather xb rows, emit mean hi/lo planes ----

__global__ void k_agg_mean(const int* __restrict__ rp, const int* __restrict__ col,
                           const uint32* __restrict__ xb,
                           short* __restrict__ mpH, short* __restrict__ mpL,
                           int N, int spl) {
    int node = blockIdx.x * 4 + (threadIdx.x >> 6);
    int lane = threadIdx.x & 63;
    if (node >= N) return;
    int beg = rp[node], end = rp[node + 1];
    float s0 = 0.f, s1 = 0.f;
    int e = beg;
    for (; e + 8 <= end; e += 8) {
        int c0 = col[e + 0], c1 = col[e + 1], c2 = col[e + 2], c3 = col[e + 3];
        int c4 = col[e + 4], c5 = col[e + 5], c6 = col[e + 6], c7 = col[e + 7];
        uint32 v0 = xb[(size_t)c0 * 64 + lane];
        uint32 v1 = xb[(size_t)c1 * 64 + lane];
        uint32 v2 = xb[(size_t)c2 * 64 + lane];
        uint32 v3 = xb[(size_t)c3 * 64 + lane];
        uint32 v4 = xb[(size_t)c4 * 64 + lane];
        uint32 v5 = xb[(size_t)c5 * 64 + lane];
        uint32 v6 = xb[(size_t)c6 * 64 + lane];
        uint32 v7 = xb[(size_t)c7 * 64 + lane];
        s0 += bf_lo(v0) + bf_lo(v1) + bf_lo(v2) + bf_lo(v3)
            + bf_lo(v4) + bf_lo(v5) + bf_lo(v6) + bf_lo(v7);
        s1 += bf_hi(v0) + bf_hi(v1) + bf_hi(v2) + bf_hi(v3)
            + bf_hi(v4) + bf_hi(v5) + bf_hi(v6) + bf_hi(v7);
    }
    for (; e < end; ++e) {
        uint32 v = xb[(size_t)col[e] * 64 + lane];
        s0 += bf_lo(v);
        s1 += bf_hi(v);
    }
    float inv = 1.0f / (float)max(end - beg, 1);
    float m0 = s0 * inv, m1 = s1 * inv;
    float b0, b1f;
    short h0 = rne16(m0, &b0);
    short l0 = rne16(m0 - b0, &b0);
    short h1 = rne16(m1, &b1f);
    short l1 = rne16(m1 - b1f, &b1f);
    int c = lane >> 2;
    int o = (2 * lane) & 7;
    size_t idx = (size_t)c * spl + (size_t)node * 8 + o;
    *(uint32*)&mpH[idx] = (uint32)(unsigned short)h0 | ((uint32)(unsigned short)h1 << 16);
    *(uint32*)&mpL[idx] = (uint32)(unsigned short)l0 | ((uint32)(unsigned short)l1 << 16);
}

// ---- MFMA GEMM 1: h = relu([mean|x] @ W1^T + b1), no LDS, no barriers ----
// Block = 128 nodes; wave w owns rows 32w..32w+31, 4 col-tiles.
// Output: h hi/lo planes (for mgemm2's B operand).

__global__ __launch_bounds__(256) void k_mgemm1(
        const short* __restrict__ mpH, const short* __restrict__ mpL,
        const short* __restrict__ xpH,
        const short* __restrict__ W1pH, const short* __restrict__ W1pL,
        const float* __restrict__ b1,
        short* __restrict__ hpH, short* __restrict__ hpL, int N, int spl) {
    int t = threadIdx.x;
    int w = t >> 6, lane = t & 63;
    int m = lane & 31, hh = lane >> 5;
    int node0 = blockIdx.x * 128;
    int myrow = node0 + 32 * w + m;
    f32x16 acc[4];
#pragma unroll
    for (int i = 0; i < 4; i++)
#pragma unroll
        for (int r = 0; r < 16; r++) acc[i][r] = 0.f;

    // seg 0: mean (3-term), k-chunks 0..15, B-planes 0..15
    for (int kc = 0; kc < 8; kc++) {
        int c = kc * 2 + hh;
        bf16x8 af = *(const bf16x8*)(mpH + (size_t)c * spl + (size_t)myrow * 8);
        bf16x8 al = *(const bf16x8*)(mpL + (size_t)c * spl + (size_t)myrow * 8);
#pragma unroll
        for (int tt = 0; tt < 4; tt++) {
            bf16x8 bh = *(const bf16x8*)(W1pH + c * 1024 + (32 * tt + m) * 8);
            bf16x8 bl = *(const bf16x8*)(W1pL + c * 1024 + (32 * tt + m) * 8);
            acc[tt] = __builtin_amdgcn_mfma_f32_32x32x16_bf16(af, bh, acc[tt], 0, 0, 0);
            acc[tt] = __builtin_amdgcn_mfma_f32_32x32x16_bf16(al, bh, acc[tt], 0, 0, 0);
            acc[tt] = __builtin_amdgcn_mfma_f32_32x32x16_bf16(af, bl, acc[tt], 0, 0, 0);
        }
    }
    // seg 1: x (2-term, x-lo dropped), B-planes 16..31
    for (int kc = 0; kc < 8; kc++) {
        int c = kc * 2 + hh;
        int cb = 16 + c;
        bf16x8 af = *(const bf16x8*)(xpH + (size_t)c * spl + (size_t)myrow * 8);
#pragma unroll
        for (int tt = 0; tt < 4; tt++) {
            bf16x8 bh = *(const bf16x8*)(W1pH + cb * 1024 + (32 * tt + m) * 8);
            bf16x8 bl = *(const bf16x8*)(W1pL + cb * 1024 + (32 * tt + m) * 8);
            acc[tt] = __builtin_amdgcn_mfma_f32_32x32x16_bf16(af, bh, acc[tt], 0, 0, 0);
            acc[tt] = __builtin_amdgcn_mfma_f32_32x32x16_bf16(af, bl, acc[tt], 0, 0, 0);
        }
    }
    // epilogue: relu(acc + b1) -> h hi/lo planes
#pragma unroll
    for (int tt = 0; tt < 4; tt++) {
        int j = 32 * tt + m;
        float bias = b1[j];
        int cj = j >> 3;
        size_t pbase = (size_t)cj * spl + (j & 7);
#pragma unroll
        for (int r = 0; r < 16; r++) {
            int row = 32 * w + (r & 3) + 8 * (r >> 2) + 4 * hh;
            int grow = node0 + row;
            if (grow < N) {
                float v = fmaxf(acc[tt][r] + bias, 0.f);
                float back;
                short hs = rne16(v, &back);
                short ls = rne16(v - back, &back);
                hpH[pbase + (size_t)grow * 8] = hs;
                hpL[pbase + (size_t)grow * 8] = ls;
            }
        }
    }
}

// ---- MFMA GEMM 2 (transposed): D^T[j][node] = W2 . h^T ----
// A = W2 planes (lane m -> j), B = h planes (lane m -> node).
// Epilogue lane owns one node -> contiguous row-major hl/hr writes.

__global__ __launch_bounds__(256) void k_mgemm2(
        const short* __restrict__ hpH, const short* __restrict__ hpL,
        const short* __restrict__ W2pH, const short* __restrict__ W2pL,
        const float* __restrict__ b2,
        unsigned short* __restrict__ hl, float* __restrict__ hr, int N, int spl) {
    int t = threadIdx.x;
    int w = t >> 6, lane = t & 63;
    int m = lane & 31, hh = lane >> 5;
    int node0 = blockIdx.x * 128;
    int mynode = node0 + 32 * w + m;
    f32x16 acc[4];
#pragma unroll
    for (int i = 0; i < 4; i++)
#pragma unroll
        for (int r = 0; r < 16; r++) acc[i][r] = 0.f;

    for (int kc = 0; kc < 8; kc++) {
        int c = kc * 2 + hh;
        bf16x8 bH = *(const bf16x8*)(hpH + (size_t)c * spl + (size_t)mynode * 8);
        bf16x8 bL = *(const bf16x8*)(hpL + (size_t)c * spl + (size_t)mynode * 8);
#pragma unroll
        for (int jt = 0; jt < 4; jt++) {
            bf16x8 wH = *(const bf16x8*)(W2pH + c * 1024 + (32 * jt + m) * 8);
            bf16x8 wL = *(const bf16x8*)(W2pL + c * 1024 + (32 * jt + m) * 8);
            acc[jt] = __builtin_amdgcn_mfma_f32_32x32x16_bf16(wH, bH, acc[jt], 0, 0, 0);
            acc[jt] = __builtin_amdgcn_mfma_f32_32x32x16_bf16(wL, bH, acc[jt], 0, 0, 0);
            acc[jt] = __builtin_amdgcn_mfma_f32_32x32x16_bf16(wH, bL, acc[jt], 0, 0, 0);
        }
    }
    if (mynode >= N) return;
    // jt 0,1 -> hl bf16 [N][64]; jt 2,3 -> hr fp32 [N][64] + b2
#pragma unroll
    for (int jt = 0; jt < 2; jt++) {
#pragma unroll
        for (int rg = 0; rg < 4; rg++) {
            int jj = 32 * jt + 8 * rg + 4 * hh;
            uint2 o;
            o.x = pack_bf16_rne(acc[jt][4 * rg + 0], acc[jt][4 * rg + 1]);
            o.y = pack_bf16_rne(acc[jt][4 * rg + 2], acc[jt][4 * rg + 3]);
            *(uint2*)&hl[(size_t)mynode * 64 + jj] = o;
        }
    }
#pragma unroll
    for (int jt = 2; jt < 4; jt++) {
#pragma unroll
        for (int rg = 0; rg < 4; rg++) {
            int jj = 32 * (jt - 2) + 8 * rg + 4 * hh;
            float4 bv = *(const float4*)(b2 + jj);
            float4 o;
            o.x = acc[jt][4 * rg + 0] + bv.x;
            o.y = acc[jt][4 * rg + 1] + bv.y;
            o.z = acc[jt][4 * rg + 2] + bv.z;
            o.w = acc[jt][4 * rg + 3] + bv.w;
            *(float4*)&hr[(size_t)mynode * 64 + jj] = o;
        }
    }
}

// ---- aggregation 2: out = mean_agg(hl) + hr ----

__global__ void k_agg_out(const int* __restrict__ rp, const int* __restrict__ col,
                          const uint32* __restrict__ hl, const float* __restrict__ hr,
                          float* __restrict__ out, int N) {
    int node = blockIdx.x * 8 + (threadIdx.x >> 5);
    int lane = threadIdx.x & 31;
    if (node >= N) return;
    int beg = rp[node], end = rp[node + 1];
    float s0 = 0.f, s1 = 0.f;
    int e = beg;
    for (; e + 8 <= end; e += 8) {
        int c0 = col[e + 0], c1 = col[e + 1], c2 = col[e + 2], c3 = col[e + 3];
        int c4 = col[e + 4], c5 = col[e + 5], c6 = col[e + 6], c7 = col[e + 7];
        uint32 v0 = hl[(size_t)c0 * 32 + lane];
        uint32 v1 = hl[(size_t)c1 * 32 + lane];
        uint32 v2 = hl[(size_t)c2 * 32 + lane];
        uint32 v3 = hl[(size_t)c3 * 32 + lane];
        uint32 v4 = hl[(size_t)c4 * 32 + lane];
        uint32 v5 = hl[(size_t)c5 * 32 + lane];
        uint32 v6 = hl[(size_t)c6 * 32 + lane];
        uint32 v7 = hl[(size_t)c7 * 32 + lane];
        s0 += bf_lo(v0) + bf_lo(v1) + bf_lo(v2) + bf_lo(v3)
            + bf_lo(v4) + bf_lo(v5) + bf_lo(v6) + bf_lo(v7);
        s1 += bf_hi(v0) + bf_hi(v1) + bf_hi(v2) + bf_hi(v3)
            + bf_hi(v4) + bf_hi(v5) + bf_hi(v6) + bf_hi(v7);
    }
    for (; e < end; ++e) {
        uint32 v = hl[(size_t)col[e] * 32 + lane];
        s0 += bf_lo(v);
        s1 += bf_hi(v);
    }
    float inv = 1.0f / (float)max(end - beg, 1);
    float2 hv = *(const float2*)(hr + (size_t)node * 64 + lane * 2);
    float2 o;
    o.x = s0 * inv + hv.x;
    o.y = s1 * inv + hv.y;
    *(float2*)(out + (size_t)node * 64 + lane * 2) = o;
}

extern "C" void kernel_launch(void* const* d_in, const int* in_sizes, int n_in,
                              void* d_out, int out_size, void* d_ws, size_t ws_size,
                              hipStream_t stream) {
    const float* x   = (const float*)d_in[0];
    const float* W1l = (const float*)d_in[1];
    const float* W1r = (const float*)d_in[2];
    const float* b1  = (const float*)d_in[3];
    const float* W2l = (const float*)d_in[4];
    const float* W2r = (const float*)d_in[5];
    const float* b2  = (const float*)d_in[6];
    const int*   ei  = (const int*)d_in[7];
    int N = in_sizes[0] / 128;
    int E = in_sizes[7] / 2;
    int NB = (N + 255) >> 8;
    int gb = (N + 127) / 128;
    int Np = gb * 128;      // padded row count for planes
    int spl = Np * 8;       // plane stride in shorts
    float* out = (float*)d_out;

    char* w = (char*)d_ws;
    size_t off = 0;
    auto alloc = [&](size_t bytes) -> char* {
        char* p = w + off;
        off += (bytes + 255) & ~(size_t)255;
        return p;
    };
    int*   row_ptr = (int*)alloc((size_t)(N + 1) * 4);
    int*   bcnt    = (int*)alloc((size_t)(NB + 1) * 4);
    int*   boff    = (int*)alloc((size_t)(NB + 1) * 4);
    int*   bcur    = (int*)alloc((size_t)(NB + 1) * 4);
    short* W1pH    = (short*)alloc(32768 * 2);
    short* W1pL    = (short*)alloc(32768 * 2);
    short* W2pH    = (short*)alloc(16384 * 2);
    short* W2pL    = (short*)alloc(16384 * 2);
    int*   col     = (int*)alloc((size_t)E * 4);
    short* xpH     = (short*)alloc((size_t)16 * spl * 2);   // 25.6 MB
    short* mpH     = (short*)alloc((size_t)16 * spl * 2);   // 25.6 MB
    short* mpL     = (short*)alloc((size_t)16 * spl * 2);   // 25.6 MB
    short* hpH     = (short*)alloc((size_t)16 * spl * 2);   // 25.6 MB
    short* hpL     = (short*)alloc((size_t)16 * spl * 2);   // 25.6 MB
    // aliases (lifetime-disjoint):
    uint32* eb   = (uint32*)hpH;              // dead before mgemm1 writes hpH
    uint32* xb   = (uint32*)hpL;              // dead (after agg_mean) before mgemm1 writes hpL
    unsigned short* hl = (unsigned short*)mpH; // mp dead after mgemm1
    float* hr    = (float*)(mpH + (size_t)N * 64); // 12.8 MB in, still inside mpH+mpL (51.2 MB)

    hipMemsetAsync(bcnt, 0, (size_t)NB * 4, stream);
    long n4 = (long)N * 32;
    k_to_bf16<<<(int)((n4 + 255) / 256), 256, 0, stream>>>(x, xb, xpH, n4, spl);
    k_wprep<<<192, 256, 0, stream>>>(W1l, W1r, W2l, W2r, W1pH, W1pL, W2pH, W2pL);
    k_bcount<<<256, 256, 0, stream>>>(ei, E, NB, bcnt);
    k_bscan<<<1, 1024, 0, stream>>>(bcnt, NB, E, boff, bcur);
    k_bscatter<<<128, 256, 0, stream>>>(ei, E, NB, bcur, eb);
    k_bfinal<<<NB, 256, 0, stream>>>(eb, boff, row_ptr, col, N, E);

    int ab = (N + 3) / 4;
    k_agg_mean<<<ab, 256, 0, stream>>>(row_ptr, col, xb, mpH, mpL, N, spl);
    k_mgemm1<<<gb, 256, 0, stream>>>(mpH, mpL, xpH, W1pH, W1pL, b1, hpH, hpL, N, spl);
    k_mgemm2<<<gb, 256, 0, stream>>>(hpH, hpL, W2pH, W2pL, b2, hl, hr, N, spl);
    int ob = (N + 7) / 8;
    k_agg_out<<<ob, 256, 0, stream>>>(row_ptr, col, (const uint32*)hl, hr, out, N);
}

// Round 6
// 393.342 us; speedup vs baseline: 1.0733x; 1.0733x over previous
//
#include <hip/hip_runtime.h>

// SAGE_Net: 2-layer GraphSAGE, N=100k, E=1.6M, 128->128->64, fp32.
// R6: wide-gather aggregation (16 B/lane uint4 gathers: 4 edges/instr for
// 128-dim rows, 8 edges/instr for 64-dim rows) + scalar col loads +
// shuffle-reduce epilogue. GEMMs stay barrier-free plane-MFMA (R5).

typedef unsigned int uint32;
typedef short bf16x4 __attribute__((ext_vector_type(4)));
typedef short bf16x8 __attribute__((ext_vector_type(8)));
typedef float f32x16 __attribute__((ext_vector_type(16)));

__device__ __forceinline__ uint32 pack_bf16_rne(float a, float b) {
    uint32 ua = __float_as_uint(a);
    uint32 ub = __float_as_uint(b);
    uint32 ra = (ua + 0x7fffu + ((ua >> 16) & 1u)) >> 16;
    uint32 rb = (ub + 0x7fffu + ((ub >> 16) & 1u)) >> 16;
    return ra | (rb << 16);
}
__device__ __forceinline__ float bf_lo(uint32 v) { return __uint_as_float(v << 16); }
__device__ __forceinline__ float bf_hi(uint32 v) { return __uint_as_float(v & 0xffff0000u); }

__device__ __forceinline__ short rne16(float v, float* back) {
    uint32 u = __float_as_uint(v);
    uint32 r = (u + 0x7fffu + ((u >> 16) & 1u)) >> 16;
    *back = __uint_as_float(r << 16);
    return (short)r;
}

__device__ __forceinline__ void acc8(float* s, uint4 v) {
    s[0] += bf_lo(v.x); s[1] += bf_hi(v.x);
    s[2] += bf_lo(v.y); s[3] += bf_hi(v.y);
    s[4] += bf_lo(v.z); s[5] += bf_hi(v.z);
    s[6] += bf_lo(v.w); s[7] += bf_hi(v.w);
}

__device__ __forceinline__ int sel4(int c0, int c1, int c2, int c3, int g) {
    int a = (g & 1) ? c1 : c0;
    int b = (g & 1) ? c3 : c2;
    return (g & 2) ? b : a;
}

// x -> xb (row-major packed bf16 hi, for gathers) + xpH (hi planes for MFMA)
__global__ void k_to_bf16(const float* __restrict__ x, uint32* __restrict__ xb,
                          short* __restrict__ xpH, long n4, int spl) {
    long i = (long)blockIdx.x * blockDim.x + threadIdx.x;
    if (i >= n4) return;
    int node = (int)(i >> 5);
    int k4 = ((int)i & 31) * 4;
    float4 v = ((const float4*)x)[i];
    float back;
    bf16x4 hi4;
    hi4[0] = rne16(v.x, &back);
    hi4[1] = rne16(v.y, &back);
    hi4[2] = rne16(v.z, &back);
    hi4[3] = rne16(v.w, &back);
    uint2 oxb;
    oxb.x = (uint32)(unsigned short)hi4[0] | ((uint32)(unsigned short)hi4[1] << 16);
    oxb.y = (uint32)(unsigned short)hi4[2] | ((uint32)(unsigned short)hi4[3] << 16);
    ((uint2*)xb)[i] = oxb;
    int c = k4 >> 3;
    *(bf16x4*)&xpH[(size_t)c * spl + (size_t)node * 8 + (k4 & 7)] = hi4;
}

__global__ void k_wprep(const float* __restrict__ W1l, const float* __restrict__ W1r,
                        const float* __restrict__ W2l, const float* __restrict__ W2r,
                        short* __restrict__ W1pH, short* __restrict__ W1pL,
                        short* __restrict__ W2pH, short* __restrict__ W2pL) {
    int i = blockIdx.x * blockDim.x + threadIdx.x;
    float back;
    if (i < 32768) {
        int j = i >> 8, k = i & 255;
        float v = (k < 128) ? W1l[j * 128 + k] : W1r[j * 128 + k - 128];
        float hb;
        short hs = rne16(v, &hb);
        short ls = rne16(v - hb, &back);
        int idx = (k >> 3) * 1024 + j * 8 + (k & 7);
        W1pH[idx] = hs;
        W1pL[idx] = ls;
    } else if (i < 32768 + 16384) {
        int i2 = i - 32768;
        int j = i2 >> 7, k = i2 & 127;
        float v = (j < 64) ? W2l[j * 128 + k] : W2r[(j - 64) * 128 + k];
        float hb;
        short hs = rne16(v, &hb);
        short ls = rne16(v - hb, &back);
        int idx = (k >> 3) * 1024 + j * 8 + (k & 7);
        W2pH[idx] = hs;
        W2pL[idx] = ls;
    }
}

// ---- bucketed CSR build (unchanged) ----

__global__ void k_bcount(const int* __restrict__ ei, int E, int NB,
                         int* __restrict__ bucket_cnt) {
    __shared__ int hist[1024];
    int t = threadIdx.x;
    for (int i = t; i < NB; i += 256) hist[i] = 0;
    __syncthreads();
    int stride = gridDim.x * 256;
    for (int e = blockIdx.x * 256 + t; e < E; e += stride)
        atomicAdd(&hist[ei[E + e] >> 8], 1);
    __syncthreads();
    for (int i = t; i < NB; i += 256) {
        int c = hist[i];
        if (c) atomicAdd(&bucket_cnt[i], c);
    }
}

__global__ void k_bscan(const int* __restrict__ bucket_cnt, int NB, int E,
                        int* __restrict__ bucket_off, int* __restrict__ bucket_cur) {
    __shared__ int s[1024];
    int t = threadIdx.x;
    int v = (t < NB) ? bucket_cnt[t] : 0;
    s[t] = v;
    __syncthreads();
    for (int o = 1; o < 1024; o <<= 1) {
        int u = (t >= o) ? s[t - o] : 0;
        __syncthreads();
        s[t] += u;
        __syncthreads();
    }
    int ex = s[t] - v;
    if (t < NB) { bucket_off[t] = ex; bucket_cur[t] = ex; }
    if (t == NB - 1) bucket_off[NB] = ex + v;
}

__global__ void k_bscatter(const int* __restrict__ ei, int E, int NB,
                           int* __restrict__ bucket_cur, uint32* __restrict__ eb) {
    __shared__ int hist[1024];
    __shared__ int base[1024];
    int t = threadIdx.x;
    for (int i = t; i < NB; i += 256) hist[i] = 0;
    __syncthreads();
    int stride = gridDim.x * 256;
    for (int e = blockIdx.x * 256 + t; e < E; e += stride)
        atomicAdd(&hist[ei[E + e] >> 8], 1);
    __syncthreads();
    for (int i = t; i < NB; i += 256) {
        int c = hist[i];
        base[i] = c ? atomicAdd(&bucket_cur[i], c) : 0;
        hist[i] = 0;
    }
    __syncthreads();
    for (int e = blockIdx.x * 256 + t; e < E; e += stride) {
        int d = ei[E + e];
        int b = d >> 8;
        int r = atomicAdd(&hist[b], 1);
        eb[base[b] + r] = ((uint32)(d & 255) << 24) | (uint32)ei[e];
    }
}

__global__ void k_bfinal(const uint32* __restrict__ eb,
                         const int* __restrict__ bucket_off,
                         int* __restrict__ row_ptr, int* __restrict__ col,
                         int N, int E) {
    __shared__ int deg[256];
    __shared__ int sc[256];
    __shared__ int cur[256];
    int b = blockIdx.x;
    int t = threadIdx.x;
    int beg = bucket_off[b], end = bucket_off[b + 1];
    deg[t] = 0;
    __syncthreads();
    for (int e = beg + t; e < end; e += 256)
        atomicAdd(&deg[eb[e] >> 24], 1);
    __syncthreads();
    int v = deg[t];
    sc[t] = v;
    __syncthreads();
    for (int o = 1; o < 256; o <<= 1) {
        int u = (t >= o) ? sc[t - o] : 0;
        __syncthreads();
        sc[t] += u;
        __syncthreads();
    }
    int ex = sc[t] - v;
    int node = b * 256 + t;
    if (node < N) row_ptr[node] = beg + ex;
    if (b == gridDim.x - 1 && t == 0) row_ptr[N] = E;
    cur[t] = ex;
    __syncthreads();
    for (int e = beg + t; e < end; e += 256) {
        uint32 u = eb[e];
        int r = atomicAdd(&cur[u >> 24], 1);
        col[beg + r] = (int)(u & 0xFFFFFFu);
    }
}

// ---- aggregation 1: wide gather (4 edges/instr), emit mean hi/lo planes ----
// wave per node; lane = (g=lane>>4 edge-subgroup, f=lane&15 feature-chunk/plane)

__global__ void k_agg_mean(const int* __restrict__ rp, const int* __restrict__ col,
                           const uint32* __restrict__ xb,
                           short* __restrict__ mpH, short* __restrict__ mpL,
                           int N, int spl) {
    int node = blockIdx.x * 4 + (threadIdx.x >> 6);
    if (node >= N) return;
    node = __builtin_amdgcn_readfirstlane(node);
    int lane = threadIdx.x & 63;
    int g = lane >> 4;
    int f = lane & 15;
    int beg = rp[node], end = rp[node + 1];
    const uint4* xb4 = (const uint4*)xb;  // row = 16 uint4
    float s[8];
#pragma unroll
    for (int j = 0; j < 8; j++) s[j] = 0.f;
    int e = beg;
    for (; e + 16 <= end; e += 16) {
        int c0 = col[e + 0], c1 = col[e + 1], c2 = col[e + 2], c3 = col[e + 3];
        int c4 = col[e + 4], c5 = col[e + 5], c6 = col[e + 6], c7 = col[e + 7];
        int c8 = col[e + 8], c9 = col[e + 9], ca = col[e + 10], cb = col[e + 11];
        int cc = col[e + 12], cd = col[e + 13], ce = col[e + 14], cf = col[e + 15];
        int s0 = sel4(c0, c1, c2, c3, g);
        int s1 = sel4(c4, c5, c6, c7, g);
        int s2 = sel4(c8, c9, ca, cb, g);
        int s3 = sel4(cc, cd, ce, cf, g);
        uint4 v0 = xb4[(size_t)s0 * 16 + f];
        uint4 v1 = xb4[(size_t)s1 * 16 + f];
        uint4 v2 = xb4[(size_t)s2 * 16 + f];
        uint4 v3 = xb4[(size_t)s3 * 16 + f];
        acc8(s, v0); acc8(s, v1); acc8(s, v2); acc8(s, v3);
    }
    for (; e + 4 <= end; e += 4) {
        int c0 = col[e + 0], c1 = col[e + 1], c2 = col[e + 2], c3 = col[e + 3];
        int s0 = sel4(c0, c1, c2, c3, g);
        uint4 v0 = xb4[(size_t)s0 * 16 + f];
        acc8(s, v0);
    }
    int rem = end - e;
    if (g < rem) {
        int s0 = col[e + g];
        uint4 v0 = xb4[(size_t)s0 * 16 + f];
        acc8(s, v0);
    }
#pragma unroll
    for (int j = 0; j < 8; j++) {
        s[j] += __shfl_xor(s[j], 16);
        s[j] += __shfl_xor(s[j], 32);
    }
    if (g == 0) {
        float inv = 1.0f / (float)max(end - beg, 1);
        uint32 H[4], L[4];
#pragma unroll
        for (int p = 0; p < 4; p++) {
            float m0 = s[2 * p] * inv, m1 = s[2 * p + 1] * inv;
            float b;
            short h0 = rne16(m0, &b);
            short l0 = rne16(m0 - b, &b);
            short h1 = rne16(m1, &b);
            short l1 = rne16(m1 - b, &b);
            H[p] = (uint32)(unsigned short)h0 | ((uint32)(unsigned short)h1 << 16);
            L[p] = (uint32)(unsigned short)l0 | ((uint32)(unsigned short)l1 << 16);
        }
        size_t idx = (size_t)f * spl + (size_t)node * 8;
        *(uint4*)&mpH[idx] = make_uint4(H[0], H[1], H[2], H[3]);
        *(uint4*)&mpL[idx] = make_uint4(L[0], L[1], L[2], L[3]);
    }
}

// ---- MFMA GEMM 1 (unchanged from R5) ----

__global__ __launch_bounds__(256) void k_mgemm1(
        const short* __restrict__ mpH, const short* __restrict__ mpL,
        const short* __restrict__ xpH,
        const short* __restrict__ W1pH, const short* __restrict__ W1pL,
        const float* __restrict__ b1,
        short* __restrict__ hpH, short* __restrict__ hpL, int N, int spl) {
    int t = threadIdx.x;
    int w = t >> 6, lane = t & 63;
    int m = lane & 31, hh = lane >> 5;
    int node0 = blockIdx.x * 128;
    int myrow = node0 + 32 * w + m;
    f32x16 acc[4];
#pragma unroll
    for (int i = 0; i < 4; i++)
#pragma unroll
        for (int r = 0; r < 16; r++) acc[i][r] = 0.f;

    for (int kc = 0; kc < 8; kc++) {
        int c = kc * 2 + hh;
        bf16x8 af = *(const bf16x8*)(mpH + (size_t)c * spl + (size_t)myrow * 8);
        bf16x8 al = *(const bf16x8*)(mpL + (size_t)c * spl + (size_t)myrow * 8);
#pragma unroll
        for (int tt = 0; tt < 4; tt++) {
            bf16x8 bh = *(const bf16x8*)(W1pH + c * 1024 + (32 * tt + m) * 8);
            bf16x8 bl = *(const bf16x8*)(W1pL + c * 1024 + (32 * tt + m) * 8);
            acc[tt] = __builtin_amdgcn_mfma_f32_32x32x16_bf16(af, bh, acc[tt], 0, 0, 0);
            acc[tt] = __builtin_amdgcn_mfma_f32_32x32x16_bf16(al, bh, acc[tt], 0, 0, 0);
            acc[tt] = __builtin_amdgcn_mfma_f32_32x32x16_bf16(af, bl, acc[tt], 0, 0, 0);
        }
    }
    for (int kc = 0; kc < 8; kc++) {
        int c = kc * 2 + hh;
        int cb = 16 + c;
        bf16x8 af = *(const bf16x8*)(xpH + (size_t)c * spl + (size_t)myrow * 8);
#pragma unroll
        for (int tt = 0; tt < 4; tt++) {
            bf16x8 bh = *(const bf16x8*)(W1pH + cb * 1024 + (32 * tt + m) * 8);
            bf16x8 bl = *(const bf16x8*)(W1pL + cb * 1024 + (32 * tt + m) * 8);
            acc[tt] = __builtin_amdgcn_mfma_f32_32x32x16_bf16(af, bh, acc[tt], 0, 0, 0);
            acc[tt] = __builtin_amdgcn_mfma_f32_32x32x16_bf16(af, bl, acc[tt], 0, 0, 0);
        }
    }
#pragma unroll
    for (int tt = 0; tt < 4; tt++) {
        int j = 32 * tt + m;
        float bias = b1[j];
        int cj = j >> 3;
        size_t pbase = (size_t)cj * spl + (j & 7);
#pragma unroll
        for (int r = 0; r < 16; r++) {
            int row = 32 * w + (r & 3) + 8 * (r >> 2) + 4 * hh;
            int grow = node0 + row;
            if (grow < N) {
                float v = fmaxf(acc[tt][r] + bias, 0.f);
                float back;
                short hs = rne16(v, &back);
                short ls = rne16(v - back, &back);
                hpH[pbase + (size_t)grow * 8] = hs;
                hpL[pbase + (size_t)grow * 8] = ls;
            }
        }
    }
}

// ---- MFMA GEMM 2 (unchanged from R5) ----

__global__ __launch_bounds__(256) void k_mgemm2(
        const short* __restrict__ hpH, const short* __restrict__ hpL,
        const short* __restrict__ W2pH, const short* __restrict__ W2pL,
        const float* __restrict__ b2,
        unsigned short* __restrict__ hl, float* __restrict__ hr, int N, int spl) {
    int t = threadIdx.x;
    int w = t >> 6, lane = t & 63;
    int m = lane & 31, hh = lane >> 5;
    int node0 = blockIdx.x * 128;
    int mynode = node0 + 32 * w + m;
    f32x16 acc[4];
#pragma unroll
    for (int i = 0; i < 4; i++)
#pragma unroll
        for (int r = 0; r < 16; r++) acc[i][r] = 0.f;

    for (int kc = 0; kc < 8; kc++) {
        int c = kc * 2 + hh;
        bf16x8 bH = *(const bf16x8*)(hpH + (size_t)c * spl + (size_t)mynode * 8);
        bf16x8 bL = *(const bf16x8*)(hpL + (size_t)c * spl + (size_t)mynode * 8);
#pragma unroll
        for (int jt = 0; jt < 4; jt++) {
            bf16x8 wH = *(const bf16x8*)(W2pH + c * 1024 + (32 * jt + m) * 8);
            bf16x8 wL = *(const bf16x8*)(W2pL + c * 1024 + (32 * jt + m) * 8);
            acc[jt] = __builtin_amdgcn_mfma_f32_32x32x16_bf16(wH, bH, acc[jt], 0, 0, 0);
            acc[jt] = __builtin_amdgcn_mfma_f32_32x32x16_bf16(wL, bH, acc[jt], 0, 0, 0);
            acc[jt] = __builtin_amdgcn_mfma_f32_32x32x16_bf16(wH, bL, acc[jt], 0, 0, 0);
        }
    }
    if (mynode >= N) return;
#pragma unroll
    for (int jt = 0; jt < 2; jt++) {
#pragma unroll
        for (int rg = 0; rg < 4; rg++) {
            int jj = 32 * jt + 8 * rg + 4 * hh;
            uint2 o;
            o.x = pack_bf16_rne(acc[jt][4 * rg + 0], acc[jt][4 * rg + 1]);
            o.y = pack_bf16_rne(acc[jt][4 * rg + 2], acc[jt][4 * rg + 3]);
            *(uint2*)&hl[(size_t)mynode * 64 + jj] = o;
        }
    }
#pragma unroll
    for (int jt = 2; jt < 4; jt++) {
#pragma unroll
        for (int rg = 0; rg < 4; rg++) {
            int jj = 32 * (jt - 2) + 8 * rg + 4 * hh;
            float4 bv = *(const float4*)(b2 + jj);
            float4 o;
            o.x = acc[jt][4 * rg + 0] + bv.x;
            o.y = acc[jt][4 * rg + 1] + bv.y;
            o.z = acc[jt][4 * rg + 2] + bv.z;
            o.w = acc[jt][4 * rg + 3] + bv.w;
            *(float4*)&hr[(size_t)mynode * 64 + jj] = o;
        }
    }
}

// ---- aggregation 2: wide gather (8 edges/instr), out = mean_agg(hl) + hr ----
// wave per node; lane = (g=lane>>3 edge-subgroup, f=lane&7 feature-chunk)

__global__ void k_agg_out(const int* __restrict__ rp, const int* __restrict__ col,
                          const uint32* __restrict__ hl, const float* __restrict__ hr,
                          float* __restrict__ out, int N) {
    int node = blockIdx.x * 4 + (threadIdx.x >> 6);
    if (node >= N) return;
    node = __builtin_amdgcn_readfirstlane(node);
    int lane = threadIdx.x & 63;
    int g = lane >> 3;
    int f = lane & 7;
    int beg = rp[node], end = rp[node + 1];
    const uint4* hl4 = (const uint4*)hl;  // row = 8 uint4
    float s[8];
#pragma unroll
    for (int j = 0; j < 8; j++) s[j] = 0.f;
    int e = beg;
    for (; e + 16 <= end; e += 16) {
        int c0 = col[e + 0], c1 = col[e + 1], c2 = col[e + 2], c3 = col[e + 3];
        int c4 = col[e + 4], c5 = col[e + 5], c6 = col[e + 6], c7 = col[e + 7];
        int c8 = col[e + 8], c9 = col[e + 9], ca = col[e + 10], cb = col[e + 11];
        int cc = col[e + 12], cd = col[e + 13], ce = col[e + 14], cf = col[e + 15];
        int lo0 = sel4(c0, c1, c2, c3, g & 3);
        int hi0 = sel4(c4, c5, c6, c7, g & 3);
        int s0 = (g < 4) ? lo0 : hi0;
        int lo1 = sel4(c8, c9, ca, cb, g & 3);
        int hi1 = sel4(cc, cd, ce, cf, g & 3);
        int s1 = (g < 4) ? lo1 : hi1;
        uint4 v0 = hl4[(size_t)s0 * 8 + f];
        uint4 v1 = hl4[(size_t)s1 * 8 + f];
        acc8(s, v0); acc8(s, v1);
    }
    for (; e + 8 <= end; e += 8) {
        int c0 = col[e + 0], c1 = col[e + 1], c2 = col[e + 2], c3 = col[e + 3];
        int c4 = col[e + 4], c5 = col[e + 5], c6 = col[e + 6], c7 = col[e + 7];
        int lo0 = sel4(c0, c1, c2, c3, g & 3);
        int hi0 = sel4(c4, c5, c6, c7, g & 3);
        int s0 = (g < 4) ? lo0 : hi0;
        uint4 v0 = hl4[(size_t)s0 * 8 + f];
        acc8(s, v0);
    }
    int rem = end - e;
    if (g < rem) {
        int s0 = col[e + g];
        uint4 v0 = hl4[(size_t)s0 * 8 + f];
        acc8(s, v0);
    }
#pragma unroll
    for (int j = 0; j < 8; j++) {
        s[j] += __shfl_xor(s[j], 8);
        s[j] += __shfl_xor(s[j], 16);
        s[j] += __shfl_xor(s[j], 32);
    }
    if (g == 0) {
        float inv = 1.0f / (float)max(end - beg, 1);
        const float* hrp = hr + (size_t)node * 64 + f * 8;
        float4 h0 = *(const float4*)(hrp);
        float4 h1 = *(const float4*)(hrp + 4);
        float4 o0, o1;
        o0.x = s[0] * inv + h0.x;
        o0.y = s[1] * inv + h0.y;
        o0.z = s[2] * inv + h0.z;
        o0.w = s[3] * inv + h0.w;
        o1.x = s[4] * inv + h1.x;
        o1.y = s[5] * inv + h1.y;
        o1.z = s[6] * inv + h1.z;
        o1.w = s[7] * inv + h1.w;
        float* op = out + (size_t)node * 64 + f * 8;
        *(float4*)(op) = o0;
        *(float4*)(op + 4) = o1;
    }
}

extern "C" void kernel_launch(void* const* d_in, const int* in_sizes, int n_in,
                              void* d_out, int out_size, void* d_ws, size_t ws_size,
                              hipStream_t stream) {
    const float* x   = (const float*)d_in[0];
    const float* W1l = (const float*)d_in[1];
    const float* W1r = (const float*)d_in[2];
    const float* b1  = (const float*)d_in[3];
    const float* W2l = (const float*)d_in[4];
    const float* W2r = (const float*)d_in[5];
    const float* b2  = (const float*)d_in[6];
    const int*   ei  = (const int*)d_in[7];
    int N = in_sizes[0] / 128;
    int E = in_sizes[7] / 2;
    int NB = (N + 255) >> 8;
    int gb = (N + 127) / 128;
    int Np = gb * 128;
    int spl = Np * 8;
    float* out = (float*)d_out;

    char* w = (char*)d_ws;
    size_t off = 0;
    auto alloc = [&](size_t bytes) -> char* {
        char* p = w + off;
        off += (bytes + 255) & ~(size_t)255;
        return p;
    };
    int*   row_ptr = (int*)alloc((size_t)(N + 1) * 4);
    int*   bcnt    = (int*)alloc((size_t)(NB + 1) * 4);
    int*   boff    = (int*)alloc((size_t)(NB + 1) * 4);
    int*   bcur    = (int*)alloc((size_t)(NB + 1) * 4);
    short* W1pH    = (short*)alloc(32768 * 2);
    short* W1pL    = (short*)alloc(32768 * 2);
    short* W2pH    = (short*)alloc(16384 * 2);
    short* W2pL    = (short*)alloc(16384 * 2);
    int*   col     = (int*)alloc((size_t)E * 4);
    short* xpH     = (short*)alloc((size_t)16 * spl * 2);
    short* mpH     = (short*)alloc((size_t)16 * spl * 2);
    short* mpL     = (short*)alloc((size_t)16 * spl * 2);
    short* hpH     = (short*)alloc((size_t)16 * spl * 2);
    short* hpL     = (short*)alloc((size_t)16 * spl * 2);
    uint32* eb   = (uint32*)hpH;
    uint32* xb   = (uint32*)hpL;
    unsigned short* hl = (unsigned short*)mpH;
    float* hr    = (float*)(mpH + (size_t)N * 64);

    hipMemsetAsync(bcnt, 0, (size_t)NB * 4, stream);
    long n4 = (long)N * 32;
    k_to_bf16<<<(int)((n4 + 255) / 256), 256, 0, stream>>>(x, xb, xpH, n4, spl);
    k_wprep<<<192, 256, 0, stream>>>(W1l, W1r, W2l, W2r, W1pH, W1pL, W2pH, W2pL);
    k_bcount<<<256, 256, 0, stream>>>(ei, E, NB, bcnt);
    k_bscan<<<1, 1024, 0, stream>>>(bcnt, NB, E, boff, bcur);
    k_bscatter<<<128, 256, 0, stream>>>(ei, E, NB, bcur, eb);
    k_bfinal<<<NB, 256, 0, stream>>>(eb, boff, row_ptr, col, N, E);

    int ab = (N + 3) / 4;
    k_agg_mean<<<ab, 256, 0, stream>>>(row_ptr, col, xb, mpH, mpL, N, spl);
    k_mgemm1<<<gb, 256, 0, stream>>>(mpH, mpL, xpH, W1pH, W1pL, b1, hpH, hpL, N, spl);
    k_mgemm2<<<gb, 256, 0, stream>>>(hpH, hpL, W2pH, W2pL, b2, hl, hr, N, spl);
    k_agg_out<<<ab, 256, 0, stream>>>(row_ptr, col, (const uint32*)hl, hr, out, N);
}